// Round 1
// baseline (179.099 us; speedup 1.0000x reference)
//
#include <hip/hip_runtime.h>
#include <cstdint>
#include <cstring>

#define B_ 32
#define N_ 128
#define F_ 128

typedef __attribute__((ext_vector_type(8))) __bf16 bf16x8;
typedef __attribute__((ext_vector_type(4))) float f32x4;

__device__ inline uint16_t f2bf_bits(float f) {
  __bf16 h = (__bf16)f;
  uint16_t u;
  __builtin_memcpy(&u, &h, 2);
  return u;
}

// ---------------- Kernel A: e_v = v_in @ W_ev + b_ev  -> ws ----------------
__global__ __launch_bounds__(128) void ev_kernel(const float* __restrict__ v_in,
                                                 const float* __restrict__ W_ev,
                                                 const float* __restrict__ b_ev,
                                                 float* __restrict__ e_v) {
  __shared__ float vr[8][F_];
  const int R0 = blockIdx.x * 8;  // 8 rows (b,n pairs) per block
  const int tid = threadIdx.x;    // = output feature g
#pragma unroll
  for (int i = 0; i < 8; ++i) vr[i][tid] = v_in[(size_t)(R0 + i) * F_ + tid];
  __syncthreads();
  float acc[8];
  const float bb = b_ev[tid];
#pragma unroll
  for (int i = 0; i < 8; ++i) acc[i] = bb;
  for (int f = 0; f < F_; ++f) {
    const float wv = W_ev[f * F_ + tid];
#pragma unroll
    for (int i = 0; i < 8; ++i) acc[i] += vr[i][f] * wv;
  }
#pragma unroll
  for (int i = 0; i < 8; ++i) e_v[(size_t)(R0 + i) * F_ + tid] = acc[i];
}

// ------- Kernel P: pack W_e (fp32 [128][128]) into bf16 MFMA B-fragments ----
// Fragment tile t = kt*8+gt (kt: k-tile of 32, gt: g-tile of 16).
// Lane l of tile t holds 8 bf16: W_e[kt*32 + 8*(l>>4) + e][gt*16 + (l&15)].
__global__ void pack_kernel(const float* __restrict__ W_e, uint32_t* __restrict__ wp) {
  const int tid = threadIdx.x;
  for (int idx = tid; idx < 2048; idx += 256) {
    const int t = idx >> 6, l = idx & 63;
    const int kt = t >> 3, gt = t & 7;
    const int kbase = kt * 32 + ((l >> 4) << 3);
    const int g = gt * 16 + (l & 15);
#pragma unroll
    for (int p = 0; p < 4; ++p) {
      const uint32_t lo = f2bf_bits(W_e[(kbase + 2 * p) * F_ + g]);
      const uint32_t hi = f2bf_bits(W_e[(kbase + 2 * p + 1) * F_ + g]);
      wp[idx * 4 + p] = lo | (hi << 16);
    }
  }
}

// ---------------- Kernel M: fused edge GEMM + epilogue + vertex out ---------
// grid = 32 (b) * 8 (n-tile of 16).  512 threads = 8 waves; wave w owns
// m in {w, w+8, ..., w+120}.  Per chunk: A = e_in[b, m, n0:n0+16, :] (16x128),
// MFMA vs W_e -> 16x128, epilogue: + e_v[b,n] + e_v[b,m] + b_e, relu,
// store e_out, accumulate per_v_e in registers (D-layout invariant over m).
__global__ __launch_bounds__(512) void main_kernel(
    const float* __restrict__ v_in, const float* __restrict__ e_in,
    const float* __restrict__ e_v, const float* __restrict__ b_e,
    const float* __restrict__ W_v, const float* __restrict__ b_v,
    const bf16x8* __restrict__ wp, float* __restrict__ v_out,
    float* __restrict__ e_out) {
  __shared__ bf16x8 wfrag[2048];      // 32 KB packed W_e
  __shared__ float comb[16][256];     // 16 KB: [per_v_e | v_in] rows

  const int tid = threadIdx.x;
  const int w = tid >> 6, l = tid & 63;
  const int b = blockIdx.x >> 3;
  const int n0 = (blockIdx.x & 7) * 16;
  const int lr = (l >> 4) << 2;  // D-row group base (0,4,8,12)
  const int lc = l & 15;         // D-col within g-tile

  // stage packed W_e into LDS (coalesced dwordx4)
  for (int i = tid; i < 2048; i += 512) wfrag[i] = wp[i];

  // per-row (n) epilogue term: e_v[b, n0+lr+q, g] + b_e[g]
  float evr[8][4];
  const float* evb = e_v + (size_t)(b * N_ + n0) * F_;
#pragma unroll
  for (int gt = 0; gt < 8; ++gt) {
    const int g = gt * 16 + lc;
    const float be = b_e[g];
#pragma unroll
    for (int q = 0; q < 4; ++q) evr[gt][q] = evb[(size_t)(lr + q) * F_ + g] + be;
  }

  float pve[8][4];
#pragma unroll
  for (int gt = 0; gt < 8; ++gt)
#pragma unroll
    for (int q = 0; q < 4; ++q) pve[gt][q] = 0.f;

  __syncthreads();

  const float* einb = e_in + (size_t)b * N_ * N_ * F_;
  float* eoutb = e_out + (size_t)b * N_ * N_ * F_;
  const float* evmb = e_v + (size_t)b * N_ * F_ + lc;

  for (int it = 0; it < 16; ++it) {
    const int m = w + (it << 3);
    // A-fragment direct from global: lane l row = n0+lc, k base = 8*(l>>4)
    const float* rowp = einb + (size_t)(m * N_ + n0 + lc) * F_ + ((l >> 4) << 3);
    f32x4 fa0[4], fa1[4];
#pragma unroll
    for (int kt = 0; kt < 4; ++kt) {
      fa0[kt] = *reinterpret_cast<const f32x4*>(rowp + kt * 32);
      fa1[kt] = *reinterpret_cast<const f32x4*>(rowp + kt * 32 + 4);
    }
    float evm[8];
#pragma unroll
    for (int gt = 0; gt < 8; ++gt) evm[gt] = evmb[(size_t)m * F_ + gt * 16];

    bf16x8 a[4];
#pragma unroll
    for (int kt = 0; kt < 4; ++kt) {
#pragma unroll
      for (int e = 0; e < 4; ++e) {
        a[kt][e] = (__bf16)fa0[kt][e];
        a[kt][e + 4] = (__bf16)fa1[kt][e];
      }
    }

    f32x4 acc[8];
#pragma unroll
    for (int gt = 0; gt < 8; ++gt) {
      acc[gt][0] = 0.f; acc[gt][1] = 0.f; acc[gt][2] = 0.f; acc[gt][3] = 0.f;
    }
#pragma unroll
    for (int kt = 0; kt < 4; ++kt)
#pragma unroll
      for (int gt = 0; gt < 8; ++gt)
        acc[gt] = __builtin_amdgcn_mfma_f32_16x16x32_bf16(
            a[kt], wfrag[(kt * 8 + gt) * 64 + l], acc[gt], 0, 0, 0);

    float* outp = eoutb + (size_t)(m * N_ + n0) * F_;
#pragma unroll
    for (int gt = 0; gt < 8; ++gt) {
      const int g = gt * 16 + lc;
#pragma unroll
      for (int q = 0; q < 4; ++q) {
        float v = acc[gt][q] + evr[gt][q] + evm[gt];
        v = fmaxf(v, 0.f);
        pve[gt][q] += v;
        outp[(size_t)(lr + q) * F_ + g] = v;
      }
    }
  }

  // cross-wave reduce per_v_e into comb[:, 0:128] (wave turn-taking)
  for (int t = 0; t < 8; ++t) {
    if (w == t) {
#pragma unroll
      for (int gt = 0; gt < 8; ++gt) {
        const int g = gt * 16 + lc;
#pragma unroll
        for (int q = 0; q < 4; ++q) {
          if (t == 0) comb[lr + q][g] = pve[gt][q];
          else comb[lr + q][g] += pve[gt][q];
        }
      }
    }
    __syncthreads();
  }

  // v_in rows into comb[:, 128:256]
  for (int idx = tid; idx < 2048; idx += 512) {
    const int r = idx >> 7, f = idx & 127;
    comb[r][128 + f] = v_in[(size_t)(b * N_ + n0 + r) * F_ + f];
  }
  __syncthreads();

  // final: v_out rows = relu(comb @ W_v + b_v), fp32 VALU (tiny)
  const int g = tid & 127, qr = tid >> 7;  // qr uniform per wave -> LDS bcast
  float a0, a1, a2, a3;
  const float bvv = b_v[g];
  a0 = a1 = a2 = a3 = bvv;
  for (int f = 0; f < 256; ++f) {
    const float wv = W_v[f * F_ + g];
    a0 += comb[qr * 4 + 0][f] * wv;
    a1 += comb[qr * 4 + 1][f] * wv;
    a2 += comb[qr * 4 + 2][f] * wv;
    a3 += comb[qr * 4 + 3][f] * wv;
  }
  float* vo = v_out + (size_t)(b * N_ + n0 + qr * 4) * F_ + g;
  vo[0 * F_] = fmaxf(a0, 0.f);
  vo[1 * F_] = fmaxf(a1, 0.f);
  vo[2 * F_] = fmaxf(a2, 0.f);
  vo[3 * F_] = fmaxf(a3, 0.f);
}

extern "C" void kernel_launch(void* const* d_in, const int* in_sizes, int n_in,
                              void* d_out, int out_size, void* d_ws, size_t ws_size,
                              hipStream_t stream) {
  const float* v_in = (const float*)d_in[0];
  const float* e_in = (const float*)d_in[1];
  const float* W_ev = (const float*)d_in[2];
  const float* b_ev = (const float*)d_in[3];
  const float* W_e  = (const float*)d_in[4];
  const float* b_e  = (const float*)d_in[5];
  const float* W_v  = (const float*)d_in[6];
  const float* b_v  = (const float*)d_in[7];

  float* out = (float*)d_out;
  float* v_out = out;                                // [32,128,128]
  float* e_out = out + (size_t)B_ * N_ * F_;         // [32,128,128,128]

  float* e_v = (float*)d_ws;                                        // 2 MB fp32
  uint32_t* wpack = (uint32_t*)((char*)d_ws + (size_t)B_ * N_ * F_ * 4);  // 32 KB

  ev_kernel<<<(B_ * N_) / 8, 128, 0, stream>>>(v_in, W_ev, b_ev, e_v);
  pack_kernel<<<1, 256, 0, stream>>>(W_e, wpack);
  main_kernel<<<B_ * 8, 512, 0, stream>>>(v_in, e_in, e_v, b_e, W_v, b_v,
                                          (const bf16x8*)wpack, v_out, e_out);
}